// Round 8
// baseline (7524.434 us; speedup 1.0000x reference)
//
#include <hip/hip_runtime.h>
#include <hip/hip_bf16.h>

#define CB 256      // batch
#define CN 256      // nodes
#define CK 3        // children per node
#define CE 256      // embedding dim
#define CH 256      // hidden dim
#define CG_ 1536    // gates = 6*CH (i, o, u, f0, f1, f2)
#define KTOT 1024   // E + K*H

typedef __attribute__((ext_vector_type(8))) short short8v;   // 8 bf16 (4 VGPR)
typedef __attribute__((ext_vector_type(4))) float float4v;   // MFMA C/D

__device__ __forceinline__ unsigned short f2bfu(float v) {
    __hip_bfloat16 h = __float2bfloat16(v);
    return __builtin_bit_cast(unsigned short, h);
}
__device__ __forceinline__ float bfu2f(unsigned short u) {
    __hip_bfloat16 h = __builtin_bit_cast(__hip_bfloat16, u);
    return __bfloat162float(h);
}

// ---------------------------------------------------------------------------
// Prep (once per call): split virtual W = [Wx_w ; Uh_w] (1024 x 1536) into
// K-major bf16 hi/lo planes Whi/Wlo [g][k] so step-kernel B-fragments are
// single contiguous 16B loads. bf16x3: w = whi + wlo captures ~16 mantissa
// bits -> fp32-class GEMM accuracy.
// ---------------------------------------------------------------------------
__global__ __launch_bounds__(256) void prep_w(
    const float* __restrict__ Wx_w,    // [256][1536]
    const float* __restrict__ Uh_w,    // [768][1536]
    unsigned short* __restrict__ Whi,  // [1536][1024]
    unsigned short* __restrict__ Wlo)  // [1536][1024]
{
    const int g = blockIdx.x;          // 0..1535
    for (int k = threadIdx.x; k < KTOT; k += 256) {
        float w = (k < CE) ? Wx_w[(size_t)k * CG_ + g]
                           : Uh_w[(size_t)(k - CE) * CG_ + g];
        unsigned short hi = f2bfu(w);
        float lo = w - bfu2f(hi);
        Whi[(size_t)g * KTOT + k] = hi;
        Wlo[(size_t)g * KTOT + k] = f2bfu(lo);
    }
}

// ---------------------------------------------------------------------------
// One tree step, MFMA bf16x3 path. 256 blocks x 384 threads (6 waves).
// Block (bi,hi) owns (16 batch x 16 hidden); gates = A(16x1024) @ Wslice.
// A staged in LDS pre-split hi/lo (pad +8 -> <=2-way bank conflict on
// ds_read_b128 fragments). Waves: np in {0,1,2} owns N-pair (2 q-tiles),
// kk in {0,1} owns a K-half; 3 independent MFMA accumulator chains per tile
// (hi*whi, hi*wlo, lo*whi); partials reduced through LDS; cell phase is the
// round-7-verified code.
// MFMA 16x16x32 layouts: A lane l: row=l&15, k=(l>>4)*8+j (k-contiguous);
// B lane l: col=l&15, k=(l>>4)*8+j; D lane l: col=l&15, row=(l>>4)*4+reg.
// ---------------------------------------------------------------------------
__global__ __launch_bounds__(384) void tree_step_mfma(
    const int* __restrict__ node_ids,          // [B][N]
    const int* __restrict__ children,          // [B][N][K]
    const float* __restrict__ emb,             // [V][E]
    const unsigned short* __restrict__ Whi,    // [1536][1024] bf16 bits
    const unsigned short* __restrict__ Wlo,    // [1536][1024] bf16 bits
    const float* __restrict__ Wx_b,            // [G]
    const float* __restrict__ Uh_b,            // [K][G]
    float* __restrict__ h_s,                   // [N][B][H] f32 history
    float* __restrict__ c_s,                   // [N][B][H] f32 history
    float* __restrict__ out,                   // [B][H] f32
    const int t)
{
    const int tid = threadIdx.x;

    const int xcd  = blockIdx.x & 7;
    const int bidx = blockIdx.x >> 3;          // 0..31
    const int hi   = xcd * 2 + (bidx & 1);     // 0..15
    const int bi   = bidx >> 1;                // 0..15
    const int b0   = bi * 16;
    const int hh0  = hi * 16;

    __shared__ unsigned short Ahi[16][KTOT + 8];   // 33 KB (pad 8 -> 2064B rows)
    __shared__ unsigned short Alo[16][KTOT + 8];   // 33 KB
    __shared__ float part[2][6][16][16];           // 12.3 KB  [kk][q][bb][jj]
    __shared__ int   nid[16];
    __shared__ float msk[16][3];
    __shared__ int   cix[16][3];

    if (tid < 16) nid[tid] = node_ids[(size_t)(b0 + tid) * CN + t];
    if (tid < 48) {
        int lb = tid / 3, k = tid - lb * 3;
        int raw = children[((size_t)(b0 + lb) * CN + t) * CK + k];
        int v = raw < t;
        msk[lb][k] = v ? 1.0f : 0.0f;
        cix[lb][k] = v ? raw : 0;
    }
    __syncthreads();

    // stage A = [x | masked child h], split hi/lo: 16 x 1024, 43 elems/thread
    for (int i = 0; i < 43; ++i) {
        int idx = tid + i * 384;
        if (idx < 16 * KTOT) {
            int row = idx >> 10;
            int col = idx & 1023;
            float v;
            if (col < CE) {
                v = emb[(size_t)nid[row] * CE + col];
            } else {
                int k  = (col - CE) >> 8;
                int hc = col & 255;
                v = 0.0f;
                if (msk[row][k] != 0.0f)
                    v = h_s[((size_t)cix[row][k] * CB + (b0 + row)) * CH + hc];
            }
            unsigned short h16 = f2bfu(v);
            Ahi[row][col] = h16;
            Alo[row][col] = f2bfu(v - bfu2f(h16));
        }
    }
    __syncthreads();

    // MFMA GEMM
    {
        const int wv    = tid >> 6;            // 0..5
        const int l     = tid & 63;
        const int np    = wv % 3;              // N-pair
        const int kk    = wv / 3;              // K-half
        const int lan15 = l & 15;
        const int k8    = (l >> 4) * 8;

        float4v acc[2][3];
        #pragma unroll
        for (int a = 0; a < 2; ++a)
            #pragma unroll
            for (int b = 0; b < 3; ++b)
                acc[a][b] = (float4v){0.f, 0.f, 0.f, 0.f};

        #pragma unroll 4
        for (int c = kk * 16; c < kk * 16 + 16; ++c) {
            const int kb = c * 32 + k8;
            short8v ahi = *(const short8v*)&Ahi[lan15][kb];
            short8v alo = *(const short8v*)&Alo[lan15][kb];
            #pragma unroll
            for (int t2 = 0; t2 < 2; ++t2) {
                const size_t gcol = (size_t)((np * 2 + t2) * CH + hh0 + lan15);
                short8v bhi = *(const short8v*)(Whi + gcol * KTOT + kb);
                short8v blo = *(const short8v*)(Wlo + gcol * KTOT + kb);
                acc[t2][0] = __builtin_amdgcn_mfma_f32_16x16x32_bf16(ahi, bhi, acc[t2][0], 0, 0, 0);
                acc[t2][1] = __builtin_amdgcn_mfma_f32_16x16x32_bf16(ahi, blo, acc[t2][1], 0, 0, 0);
                acc[t2][2] = __builtin_amdgcn_mfma_f32_16x16x32_bf16(alo, bhi, acc[t2][2], 0, 0, 0);
            }
        }
        #pragma unroll
        for (int t2 = 0; t2 < 2; ++t2)
            #pragma unroll
            for (int r = 0; r < 4; ++r)
                part[kk][np * 2 + t2][(l >> 4) * 4 + r][lan15] =
                    acc[t2][0][r] + acc[t2][1][r] + acc[t2][2][r];
    }
    __syncthreads();

    // cell phase (round-7-verified)
    if (tid < 256) {
        const int bb = tid >> 4, j2 = tid & 15;
        const int b = b0 + bb, hh = hh0 + j2;
        const float m0 = msk[bb][0], m1 = msk[bb][1], m2 = msk[bb][2];
        float g[6];
        #pragma unroll
        for (int q = 0; q < 6; ++q) {
            int gc = q * CH + hh;
            g[q] = part[0][q][bb][j2] + part[1][q][bb][j2]
                 + Wx_b[gc] + m0 * Uh_b[gc] + m1 * Uh_b[CG_ + gc]
                            + m2 * Uh_b[2 * CG_ + gc];
        }
        float ig = 1.0f / (1.0f + expf(-g[0]));
        float og = 1.0f / (1.0f + expf(-g[1]));
        float ug = tanhf(g[2]);
        float c = ig * ug;
        if (m0 != 0.0f) c += (1.0f / (1.0f + expf(-g[3]))) * c_s[((size_t)cix[bb][0] * CB + b) * CH + hh];
        if (m1 != 0.0f) c += (1.0f / (1.0f + expf(-g[4]))) * c_s[((size_t)cix[bb][1] * CB + b) * CH + hh];
        if (m2 != 0.0f) c += (1.0f / (1.0f + expf(-g[5]))) * c_s[((size_t)cix[bb][2] * CB + b) * CH + hh];
        float h = og * tanhf(c);
        h_s[((size_t)t * CB + b) * CH + hh] = h;
        c_s[((size_t)t * CB + b) * CH + hh] = c;
        if (t == CN - 1) out[(size_t)b * CH + hh] = h;
    }
}

// ---------------------------------------------------------------------------
// Fallback: round-7-verified pure-fp32 step kernel (used if ws too small for
// the Whi/Wlo planes). 256 blocks x 512 threads.
// ---------------------------------------------------------------------------
__global__ __launch_bounds__(512) void tree_step(
    const int* __restrict__ node_ids, const int* __restrict__ children,
    const float* __restrict__ emb, const float* __restrict__ Wx_w,
    const float* __restrict__ Wx_b, const float* __restrict__ Uh_w,
    const float* __restrict__ Uh_b, float* __restrict__ h_s,
    float* __restrict__ c_s, float* __restrict__ out, const int t)
{
    const int tid = threadIdx.x;
    const int xcd  = blockIdx.x & 7;
    const int bidx = blockIdx.x >> 3;
    const int hi   = xcd * 2 + (bidx & 1);
    const int bi   = bidx >> 1;
    const int b0   = bi * 16;
    const int hh0  = hi * 16;
    const int tt   = tid >> 6;
    const int lane = tid & 63;
    const int bq   = lane >> 4;
    const int jj   = lane & 15;

    __shared__ float xh[16][1025];
    __shared__ float gred[8][16][6][16];
    __shared__ int   nid[16];
    __shared__ float msk[16][3];
    __shared__ int   cix[16][3];

    if (tid < 16) nid[tid] = node_ids[(size_t)(b0 + tid) * CN + t];
    if (tid < 48) {
        int lb = tid / 3, k = tid - lb * 3;
        int raw = children[((size_t)(b0 + lb) * CN + t) * CK + k];
        int v = raw < t;
        msk[lb][k] = v ? 1.0f : 0.0f;
        cix[lb][k] = v ? raw : 0;
    }
    __syncthreads();
    for (int i = 0; i < 32; ++i) {
        int id2 = tid + (i << 9);
        int lb  = id2 >> 10;
        int col = id2 & 1023;
        float v;
        if (col < CE) v = emb[(size_t)nid[lb] * CE + col];
        else {
            int k  = (col - CE) >> 8;
            int hc = col & 255;
            v = 0.0f;
            if (msk[lb][k] != 0.0f)
                v = h_s[((size_t)cix[lb][k] * CB + (b0 + lb)) * CH + hc];
        }
        xh[lb][col] = v;
    }
    __syncthreads();
    float acc[4][6] = {};
    {
        const float* w0p = (tt < 2)
            ? (Wx_w + (size_t)(tt * 128) * CG_ + (hh0 + jj))
            : (Uh_w + (size_t)(tt * 128 - 256) * CG_ + (hh0 + jj));
        const int colbase = tt * 128;
        #pragma unroll 4
        for (int kl = 0; kl < 128; ++kl) {
            const float* wr = w0p + (size_t)kl * CG_;
            float w0 = wr[0], w1 = wr[256], w2 = wr[512];
            float w3 = wr[768], w4 = wr[1024], w5 = wr[1280];
            int col = colbase + kl;
            #pragma unroll
            for (int r = 0; r < 4; ++r) {
                float hv = xh[bq + 4 * r][col];
                acc[r][0] += hv * w0; acc[r][1] += hv * w1; acc[r][2] += hv * w2;
                acc[r][3] += hv * w3; acc[r][4] += hv * w4; acc[r][5] += hv * w5;
            }
        }
    }
    #pragma unroll
    for (int r = 0; r < 4; ++r)
        #pragma unroll
        for (int q = 0; q < 6; ++q)
            gred[tt][bq + 4 * r][q][jj] = acc[r][q];
    __syncthreads();
    if (tid < 256) {
        const int bb = tid >> 4, j2 = tid & 15;
        const int b = b0 + bb, hh = hh0 + j2;
        float g[6];
        #pragma unroll
        for (int q = 0; q < 6; ++q) {
            float s = 0.0f;
            #pragma unroll
            for (int k = 0; k < 8; ++k) s += gred[k][bb][q][j2];
            g[q] = s;
        }
        const float m0 = msk[bb][0], m1 = msk[bb][1], m2 = msk[bb][2];
        #pragma unroll
        for (int q = 0; q < 6; ++q) {
            int gc = q * CH + hh;
            g[q] += Wx_b[gc] + m0 * Uh_b[gc] + m1 * Uh_b[CG_ + gc]
                             + m2 * Uh_b[2 * CG_ + gc];
        }
        float ig = 1.0f / (1.0f + expf(-g[0]));
        float og = 1.0f / (1.0f + expf(-g[1]));
        float ug = tanhf(g[2]);
        float c = ig * ug;
        if (m0 != 0.0f) c += (1.0f / (1.0f + expf(-g[3]))) * c_s[((size_t)cix[bb][0] * CB + b) * CH + hh];
        if (m1 != 0.0f) c += (1.0f / (1.0f + expf(-g[4]))) * c_s[((size_t)cix[bb][1] * CB + b) * CH + hh];
        if (m2 != 0.0f) c += (1.0f / (1.0f + expf(-g[5]))) * c_s[((size_t)cix[bb][2] * CB + b) * CH + hh];
        float h = og * tanhf(c);
        h_s[((size_t)t * CB + b) * CH + hh] = h;
        c_s[((size_t)t * CB + b) * CH + hh] = c;
        if (t == CN - 1) out[(size_t)b * CH + hh] = h;
    }
}

__global__ void ws_report(float* out, int n, float val) {
    int i = blockIdx.x * blockDim.x + threadIdx.x;
    if (i < n) out[i] = val;
}

// ---------------------------------------------------------------------------
extern "C" void kernel_launch(void* const* d_in, const int* in_sizes, int n_in,
                              void* d_out, int out_size, void* d_ws, size_t ws_size,
                              hipStream_t stream) {
    float* outp = (float*)d_out;

    const int expect_sizes[7] = {65536, 196608, 8192000, 393216, 1536, 1179648, 4608};
    int bad = -1;
    if (n_in != 7) bad = 7;
    else for (int i = 0; i < 7; ++i) if (in_sizes[i] != expect_sizes[i]) { bad = i; break; }
    if (bad >= 0) {
        ws_report<<<(out_size + 255) / 256, 256, 0, stream>>>(outp, out_size, 1000.0f + bad);
        return;
    }

    const int*   node_ids = (const int*)d_in[0];
    const int*   children = (const int*)d_in[1];
    const float* emb      = (const float*)d_in[2];
    const float* Wx_w     = (const float*)d_in[3];
    const float* Wx_b     = (const float*)d_in[4];
    const float* Uh_w     = (const float*)d_in[5];
    const float* Uh_b     = (const float*)d_in[6];

    const size_t w_plane   = (size_t)CG_ * KTOT * 2;        // 3,145,728 B
    const size_t state_sz  = (size_t)CN * CB * CH * 4;      // 67,108,864 B
    const size_t need_mfma = 2 * w_plane + 2 * state_sz;    // 140,509,184 B
    const size_t need_plain = 2 * state_sz;                 // 134,217,728 B

    if (ws_size >= need_mfma) {
        unsigned short* Whi = (unsigned short*)d_ws;
        unsigned short* Wlo = (unsigned short*)((char*)d_ws + w_plane);
        float* h_s = (float*)((char*)d_ws + 2 * w_plane);
        float* c_s = (float*)((char*)d_ws + 2 * w_plane + state_sz);
        prep_w<<<dim3(CG_), dim3(256), 0, stream>>>(Wx_w, Uh_w, Whi, Wlo);
        for (int t = 0; t < CN; ++t)
            tree_step_mfma<<<dim3(256), dim3(384), 0, stream>>>(
                node_ids, children, emb, Whi, Wlo, Wx_b, Uh_b,
                h_s, c_s, outp, t);
    } else if (ws_size >= need_plain) {
        float* h_s = (float*)d_ws;
        float* c_s = (float*)((char*)d_ws + state_sz);
        for (int t = 0; t < CN; ++t)
            tree_step<<<dim3(256), dim3(512), 0, stream>>>(
                node_ids, children, emb, Wx_w, Wx_b, Uh_w, Uh_b,
                h_s, c_s, outp, t);
    } else {
        ws_report<<<(out_size + 255) / 256, 256, 0, stream>>>(
            outp, out_size, (float)(ws_size >> 20));
    }
}